// Round 1
// baseline (610.896 us; speedup 1.0000x reference)
//
#include <hip/hip_runtime.h>

typedef unsigned short u16;
typedef unsigned int u32;
typedef __attribute__((ext_vector_type(8))) short short8;
typedef __attribute__((ext_vector_type(4))) float f32x4;

#define NB 4096
#define LDIM 8192
#define HDIM 256
#define NEXP 3
#define NCH 8

__device__ inline u16 f2bf(float f) {
  u32 u = __float_as_uint(f);
  u += 0x7FFFu + ((u >> 16) & 1u);
  return (u16)(u >> 16);
}
__device__ inline u32 pack2(float x, float y) {
  return (u32)f2bf(x) | ((u32)f2bf(y) << 16);
}

// ---------------- Kernel 1: per-channel quantile thresholds ----------------
__global__ void thresh_kernel(const float* __restrict__ q, const int* __restrict__ ch,
                              float* __restrict__ uq_th, float* __restrict__ lq_th) {
  int c = blockIdx.x;
  int tid = threadIdx.x;
  __shared__ float vals[1536];
  __shared__ int oidx[1536];
  __shared__ int n_sh;
  if (tid == 0) n_sh = 0;
  __syncthreads();
  for (int i = tid; i < NB; i += 256) {
    if (ch[i] == c) {
      int p = atomicAdd(&n_sh, 1);
      if (p < 1536) { vals[p] = q[i]; oidx[p] = i; }
    }
  }
  __syncthreads();
  int n = n_sh < 1536 ? n_sh : 1536;
  float nf = (float)n_sh;
  // match jnp f32 arithmetic exactly
  float au = ceilf((nf + 1.0f) * 0.9f) / nf;
  float pu = (au > 1.0f) ? 0.9f : au;
  int iu = (int)floorf(pu * (nf - 1.0f));
  float al = floorf((nf + 1.0f) * 0.1f) / nf;
  float pl = (al < 0.0f) ? 0.1f : al;
  int il = (int)floorf(pl * (nf - 1.0f));
  for (int e = tid; e < n; e += 256) {
    float v = vals[e];
    int oi = oidx[e];
    int r = 0;
    for (int m = 0; m < n; ++m) {
      float vm = vals[m];
      if (vm < v || (vm == v && oidx[m] < oi)) r++;
    }
    if (r == iu) uq_th[c] = v;
    if (r == il) lq_th[c] = v;
  }
}

// ---------------- Kernel 2: group assignment + expert index lists ----------------
__global__ void group_kernel(const float* __restrict__ q, const int* __restrict__ ch,
                             const float* __restrict__ uq_th, const float* __restrict__ lq_th,
                             int* __restrict__ group, int* __restrict__ cnt, int* __restrict__ idxl) {
  int b = blockIdx.x * 256 + threadIdx.x;
  if (b >= NB) return;
  float qq = q[b];
  int c = ch[b];
  // lower (2) wins over upper (0) on overlap, else normal (1)
  int g = (qq <= lq_th[c]) ? 2 : ((qq >= uq_th[c]) ? 0 : 1);
  group[b] = g;
  int pos = atomicAdd(&cnt[g], 1);
  idxl[g * NB + pos] = b;
}

// ---------------- Kernel 3: v[k][h] = W2[k][h][:] . Wh[k][:] ----------------
__global__ void v_kernel(const float* __restrict__ W2, const float* __restrict__ Wh,
                         float* __restrict__ v) {
  int wv = blockIdx.x * 4 + (threadIdx.x >> 6);  // 0..767
  int lane = threadIdx.x & 63;
  int k = wv >> 8, h = wv & 255;
  const float4* w2 = (const float4*)(W2 + ((size_t)k * HDIM + h) * LDIM);
  const float4* wh = (const float4*)(Wh + (size_t)k * LDIM);
  float s = 0.f;
  for (int i = lane; i < LDIM / 4; i += 64) {
    float4 a = w2[i], b = wh[i];
    s += a.x * b.x + a.y * b.y + a.z * b.z + a.w * b.w;
  }
  for (int off = 32; off; off >>= 1) s += __shfl_down(s, off);
  if (lane == 0) v[k * HDIM + h] = s;
}

// ---------------- Kernel 3b: cbias[k] = b2[k].Wh[k] + bh[k] ----------------
__global__ void cbias_kernel(const float* __restrict__ b2, const float* __restrict__ Wh,
                             const float* __restrict__ bh, float* __restrict__ cbias) {
  int k = threadIdx.x >> 6, lane = threadIdx.x & 63;
  float s = 0.f;
  for (int l = lane; l < LDIM; l += 64) s += b2[k * LDIM + l] * Wh[k * LDIM + l];
  for (int off = 32; off; off >>= 1) s += __shfl_down(s, off);
  if (lane == 0) cbias[k] = s + bh[k];
}

// ---------------- Kernel 4: W1 (K,L,H) f32 -> W1t (K,H,L) bf16 ----------------
__global__ void transpose_kernel(const float* __restrict__ W1, u16* __restrict__ W1t) {
  __shared__ float tile[32][33];
  int k = blockIdx.z;
  int l0 = blockIdx.x * 32;
  int h0 = blockIdx.y * 32;
  int t = threadIdx.x;
  const float* src = W1 + (size_t)k * LDIM * HDIM;
  u16* dst = W1t + (size_t)k * HDIM * LDIM;
#pragma unroll
  for (int r = 0; r < 4; ++r) {
    int ll = r * 8 + (t >> 5);
    int hh = t & 31;
    tile[ll][hh] = src[(size_t)(l0 + ll) * HDIM + h0 + hh];
  }
  __syncthreads();
#pragma unroll
  for (int r = 0; r < 4; ++r) {
    int hh = r * 8 + (t >> 5);
    int ll = t & 31;
    dst[(size_t)(h0 + hh) * LDIM + l0 + ll] = f2bf(tile[ll][hh]);
  }
}

// ---------------- Kernel 5: gathered GEMM + gelu + dot(v) -> logits ----------------
__global__ void __launch_bounds__(256) gemm_kernel(
    const float* __restrict__ z, const u16* __restrict__ W1t,
    const float* __restrict__ b1, const int* __restrict__ idxl,
    const int* __restrict__ cnt, const float* __restrict__ v,
    float* __restrict__ logits) {
  int kexp = blockIdx.z;
  int nk = cnt[kexp];
  int rowbase = blockIdx.x * 64;
  if (rowbase >= nk) return;
  int h0 = blockIdx.y * 64;
  int tid = threadIdx.x;

  __shared__ __align__(16) u16 As[64 * 64];
  __shared__ __align__(16) u16 Bs[64 * 64];
  __shared__ float Ps[64 * 65];

  const int* idxk = idxl + kexp * NB;
  int r0 = tid >> 3;  // 0..31
  int r1 = r0 + 32;
  int kg = tid & 7;
  int p0 = rowbase + r0; if (p0 > nk - 1) p0 = nk - 1;
  int p1 = rowbase + r1; if (p1 > nk - 1) p1 = nk - 1;
  const float* zr0 = z + (size_t)idxk[p0] * LDIM + kg * 8;
  const float* zr1 = z + (size_t)idxk[p1] * LDIM + kg * 8;
  const u16* w0 = W1t + ((size_t)kexp * HDIM + h0 + r0) * LDIM + kg * 8;
  const u16* w1 = W1t + ((size_t)kexp * HDIM + h0 + r1) * LDIM + kg * 8;
  // XOR-swizzled LDS offsets (u16 units); 16B-granular swizzle within 8-row stripe
  int sw0 = r0 * 64 + ((kg * 8) ^ ((r0 & 7) * 8));
  int sw1 = r1 * 64 + ((kg * 8) ^ ((r1 & 7) * 8));

  int lane = tid & 63;
  int wv = tid >> 6;
  int wr = (wv >> 1) * 32;
  int wc = (wv & 1) * 32;
  int fr = lane & 15;
  int kgl = (lane >> 4) * 8;

  f32x4 acc[2][2] = {};

  for (int kt = 0; kt < LDIM; kt += 64) {
    float4 a0 = *(const float4*)(zr0 + kt);
    float4 a1 = *(const float4*)(zr0 + kt + 4);
    float4 a2 = *(const float4*)(zr1 + kt);
    float4 a3 = *(const float4*)(zr1 + kt + 4);
    uint4 bw0 = *(const uint4*)(w0 + kt);
    uint4 bw1 = *(const uint4*)(w1 + kt);
    uint4 pa0, pa1;
    pa0.x = pack2(a0.x, a0.y); pa0.y = pack2(a0.z, a0.w);
    pa0.z = pack2(a1.x, a1.y); pa0.w = pack2(a1.z, a1.w);
    pa1.x = pack2(a2.x, a2.y); pa1.y = pack2(a2.z, a2.w);
    pa1.z = pack2(a3.x, a3.y); pa1.w = pack2(a3.z, a3.w);
    *(uint4*)&As[sw0] = pa0;
    *(uint4*)&As[sw1] = pa1;
    *(uint4*)&Bs[sw0] = bw0;
    *(uint4*)&Bs[sw1] = bw1;
    __syncthreads();
#pragma unroll
    for (int ks = 0; ks < 2; ++ks) {
      int kk = ks * 32 + kgl;
      int ra0 = wr + fr, ra1 = wr + 16 + fr;
      int ca0 = wc + fr, ca1 = wc + 16 + fr;
      short8 af0 = *(const short8*)&As[ra0 * 64 + (kk ^ ((ra0 & 7) * 8))];
      short8 af1 = *(const short8*)&As[ra1 * 64 + (kk ^ ((ra1 & 7) * 8))];
      short8 bf0 = *(const short8*)&Bs[ca0 * 64 + (kk ^ ((ca0 & 7) * 8))];
      short8 bf1 = *(const short8*)&Bs[ca1 * 64 + (kk ^ ((ca1 & 7) * 8))];
      acc[0][0] = __builtin_amdgcn_mfma_f32_16x16x32_bf16(af0, bf0, acc[0][0], 0, 0, 0);
      acc[0][1] = __builtin_amdgcn_mfma_f32_16x16x32_bf16(af0, bf1, acc[0][1], 0, 0, 0);
      acc[1][0] = __builtin_amdgcn_mfma_f32_16x16x32_bf16(af1, bf0, acc[1][0], 0, 0, 0);
      acc[1][1] = __builtin_amdgcn_mfma_f32_16x16x32_bf16(af1, bf1, acc[1][1], 0, 0, 0);
    }
    __syncthreads();
  }

  // epilogue: + b1, exact gelu, * v[col], row-reduce, atomicAdd into logits
  const float* b1g = b1 + kexp * HDIM + h0;
  const float* vg = v + kexp * HDIM + h0;
  float bc[2], vc[2];
#pragma unroll
  for (int cb = 0; cb < 2; ++cb) {
    int col = wc + cb * 16 + fr;
    bc[cb] = b1g[col];
    vc[cb] = vg[col];
  }
#pragma unroll
  for (int rb = 0; rb < 2; ++rb)
#pragma unroll
    for (int cb = 0; cb < 2; ++cb)
#pragma unroll
      for (int i = 0; i < 4; ++i) {
        int row = wr + rb * 16 + (lane >> 4) * 4 + i;
        int col = wc + cb * 16 + fr;
        float x = acc[rb][cb][i] + bc[cb];
        float g = 0.5f * x * (1.0f + erff(x * 0.70710678118654752f));
        Ps[row * 65 + col] = g * vc[cb];
      }
  __syncthreads();
  if (tid < 64) {
    int p = rowbase + tid;
    if (p < nk) {
      float s = 0.f;
#pragma unroll 8
      for (int j = 0; j < 64; ++j) s += Ps[tid * 65 + j];
      atomicAdd(&logits[idxk[p]], s);
    }
  }
}

// ---------------- Kernel 6: per-channel softmax * q ----------------
__global__ void softmax_kernel(const float* __restrict__ logits, const float* __restrict__ cbias,
                               const int* __restrict__ group, const float* __restrict__ q,
                               const int* __restrict__ ch, float* __restrict__ out) {
  int c = blockIdx.x;
  int tid = threadIdx.x;
  __shared__ float red[256];
  float m = -3.4e38f;
  for (int i = tid; i < NB; i += 256)
    if (ch[i] == c) {
      float x = logits[i] + cbias[group[i]];
      m = fmaxf(m, x);
    }
  red[tid] = m;
  __syncthreads();
  for (int s = 128; s > 0; s >>= 1) {
    if (tid < s) red[tid] = fmaxf(red[tid], red[tid + s]);
    __syncthreads();
  }
  m = red[0];
  __syncthreads();
  float sum = 0.f;
  for (int i = tid; i < NB; i += 256)
    if (ch[i] == c) sum += expf(logits[i] + cbias[group[i]] - m);
  red[tid] = sum;
  __syncthreads();
  for (int s = 128; s > 0; s >>= 1) {
    if (tid < s) red[tid] += red[tid + s];
    __syncthreads();
  }
  float S = red[0];
  for (int i = tid; i < NB; i += 256)
    if (ch[i] == c) out[i] = q[i] * expf(logits[i] + cbias[group[i]] - m) / S;
}

extern "C" void kernel_launch(void* const* d_in, const int* in_sizes, int n_in,
                              void* d_out, int out_size, void* d_ws, size_t ws_size,
                              hipStream_t stream) {
  const float* z  = (const float*)d_in[0];
  const float* q  = (const float*)d_in[1];
  const int*   ch = (const int*)d_in[2];
  const float* W1 = (const float*)d_in[3];
  const float* b1 = (const float*)d_in[4];
  const float* W2 = (const float*)d_in[5];
  const float* b2 = (const float*)d_in[6];
  const float* Wh = (const float*)d_in[7];
  const float* bh = (const float*)d_in[8];
  float* out = (float*)d_out;

  float* wsf    = (float*)d_ws;
  float* logits = wsf;                  // 4096 f32
  int*   cnt    = (int*)(wsf + 4096);   // 4 int
  float* uq_th  = wsf + 4100;           // 8
  float* lq_th  = wsf + 4108;           // 8
  float* cbias  = wsf + 4116;           // 4
  float* v      = wsf + 4120;           // 768
  int*   group  = (int*)(wsf + 4888);   // 4096 int
  int*   idxl   = (int*)(wsf + 8984);   // 3*4096 int
  u16*   W1t    = (u16*)(wsf + 21272);  // 3*256*8192 bf16 (byte off 85088, 16B aligned)

  hipMemsetAsync(d_ws, 0, 16400, stream);  // zero logits + cnt
  hipLaunchKernelGGL(thresh_kernel, dim3(NCH), dim3(256), 0, stream, q, ch, uq_th, lq_th);
  hipLaunchKernelGGL(group_kernel, dim3(16), dim3(256), 0, stream, q, ch, uq_th, lq_th, group, cnt, idxl);
  hipLaunchKernelGGL(v_kernel, dim3(192), dim3(256), 0, stream, W2, Wh, v);
  hipLaunchKernelGGL(cbias_kernel, dim3(1), dim3(192), 0, stream, b2, Wh, bh, cbias);
  hipLaunchKernelGGL(transpose_kernel, dim3(256, 8, 3), dim3(256), 0, stream, W1, W1t);
  hipLaunchKernelGGL(gemm_kernel, dim3(64, 4, 3), dim3(256), 0, stream, z, W1t, b1, idxl, cnt, v, logits);
  hipLaunchKernelGGL(softmax_kernel, dim3(NCH), dim3(256), 0, stream, logits, cbias, group, q, ch, out);
}

// Round 3
// 542.222 us; speedup vs baseline: 1.1267x; 1.1267x over previous
//
#include <hip/hip_runtime.h>

typedef unsigned short u16;
typedef unsigned int u32;
typedef __attribute__((ext_vector_type(8))) short short8;
typedef __attribute__((ext_vector_type(4))) float f32x4;

#define NB 4096
#define LDIM 8192
#define HDIM 256
#define NEXP 3
#define NCH 8
#define KSPLIT 4
#define KSLICE (LDIM / KSPLIT) /* 2048 */
#define BK 64
#define NT (KSLICE / BK) /* 32 */

__device__ inline u16 f2bf(float f) {
  u32 u = __float_as_uint(f);
  u += 0x7FFFu + ((u >> 16) & 1u);
  return (u16)(u >> 16);
}
__device__ inline u32 pack2(float x, float y) {
  return (u32)f2bf(x) | ((u32)f2bf(y) << 16);
}
__device__ inline void gll16(const void* g, void* l) {
  __builtin_amdgcn_global_load_lds((const __attribute__((address_space(1))) void*)g,
                                   (__attribute__((address_space(3))) void*)l, 16, 0, 0);
}

// ---------------- Kernel 1: per-channel quantile thresholds ----------------
__global__ void thresh_kernel(const float* __restrict__ q, const int* __restrict__ ch,
                              float* __restrict__ uq_th, float* __restrict__ lq_th) {
  int c = blockIdx.x;
  int tid = threadIdx.x;
  __shared__ float vals[1536];
  __shared__ int oidx[1536];
  __shared__ int n_sh;
  if (tid == 0) n_sh = 0;
  __syncthreads();
  for (int i = tid; i < NB; i += 256) {
    if (ch[i] == c) {
      int p = atomicAdd(&n_sh, 1);
      if (p < 1536) { vals[p] = q[i]; oidx[p] = i; }
    }
  }
  __syncthreads();
  int n = n_sh < 1536 ? n_sh : 1536;
  float nf = (float)n_sh;
  float au = ceilf((nf + 1.0f) * 0.9f) / nf;
  float pu = (au > 1.0f) ? 0.9f : au;
  int iu = (int)floorf(pu * (nf - 1.0f));
  float al = floorf((nf + 1.0f) * 0.1f) / nf;
  float pl = (al < 0.0f) ? 0.1f : al;
  int il = (int)floorf(pl * (nf - 1.0f));
  for (int e = tid; e < n; e += 256) {
    float v = vals[e];
    int oi = oidx[e];
    int r = 0;
    for (int m = 0; m < n; ++m) {
      float vm = vals[m];
      if (vm < v || (vm == v && oidx[m] < oi)) r++;
    }
    if (r == iu) uq_th[c] = v;
    if (r == il) lq_th[c] = v;
  }
}

// ---------------- Kernel 2: group assignment + expert index lists ----------------
__global__ void group_kernel(const float* __restrict__ q, const int* __restrict__ ch,
                             const float* __restrict__ uq_th, const float* __restrict__ lq_th,
                             int* __restrict__ group, int* __restrict__ cnt, int* __restrict__ idxl) {
  int b = blockIdx.x * 256 + threadIdx.x;
  if (b >= NB) return;
  float qq = q[b];
  int c = ch[b];
  int g = (qq <= lq_th[c]) ? 2 : ((qq >= uq_th[c]) ? 0 : 1);
  group[b] = g;
  int pos = atomicAdd(&cnt[g], 1);
  idxl[g * NB + pos] = b;
}

// ---------------- Kernel 3: v[k][h] = W2[k][h][:] . Wh[k][:] ----------------
__global__ void v_kernel(const float* __restrict__ W2, const float* __restrict__ Wh,
                         float* __restrict__ v) {
  int wv = blockIdx.x * 4 + (threadIdx.x >> 6);  // 0..767
  int lane = threadIdx.x & 63;
  int k = wv >> 8, h = wv & 255;
  const float4* w2 = (const float4*)(W2 + ((size_t)k * HDIM + h) * LDIM);
  const float4* wh = (const float4*)(Wh + (size_t)k * LDIM);
  float s = 0.f;
  for (int i = lane; i < LDIM / 4; i += 64) {
    float4 a = w2[i], b = wh[i];
    s += a.x * b.x + a.y * b.y + a.z * b.z + a.w * b.w;
  }
  for (int off = 32; off; off >>= 1) s += __shfl_down(s, off);
  if (lane == 0) v[k * HDIM + h] = s;
}

// ---------------- Kernel 3b: cbias[k] = b2[k].Wh[k] + bh[k] ----------------
__global__ void cbias_kernel(const float* __restrict__ b2, const float* __restrict__ Wh,
                             const float* __restrict__ bh, float* __restrict__ cbias) {
  int k = threadIdx.x >> 6, lane = threadIdx.x & 63;
  float s = 0.f;
  for (int l = lane; l < LDIM; l += 64) s += b2[k * LDIM + l] * Wh[k * LDIM + l];
  for (int off = 32; off; off >>= 1) s += __shfl_down(s, off);
  if (lane == 0) cbias[k] = s + bh[k];
}

// ---------------- Kernel 4: W1 (K,L,H) f32 -> W1t (K,H,L) bf16 ----------------
// 64x64 tiles; coalesced f32 reads, short8 (16B) stores, padded LDS (bank-conflict-free).
__global__ void transpose_kernel(const float* __restrict__ W1, u16* __restrict__ W1t) {
  __shared__ float tile[64][65];
  int k = blockIdx.z;
  int l0 = blockIdx.x * 64;
  int h0 = blockIdx.y * 64;
  int t = threadIdx.x;
  const float* src = W1 + (size_t)k * LDIM * HDIM + (size_t)l0 * HDIM + h0;
  u16* dst = W1t + (size_t)k * HDIM * LDIM + (size_t)h0 * LDIM + l0;
  int hr = t & 63, lr = t >> 6;
#pragma unroll
  for (int p = 0; p < 16; ++p) {
    int l = p * 4 + lr;
    tile[l][hr] = src[(size_t)l * HDIM + hr];
  }
  __syncthreads();
  int cw = t & 7, hw = t >> 3;  // 32 h-rows per pass
#pragma unroll
  for (int p = 0; p < 2; ++p) {
    int h = p * 32 + hw;
    short8 v8;
#pragma unroll
    for (int j = 0; j < 8; ++j) v8[j] = (short)f2bf(tile[cw * 8 + j][h]);
    *(short8*)&dst[(size_t)h * LDIM + cw * 8] = v8;
  }
}

// ---------------- Kernel 5: gathered K-split GEMM -> part[s][b][h] ----------------
__global__ void __launch_bounds__(256) gemm_kernel(
    const float* __restrict__ z, const u16* __restrict__ W1t,
    const int* __restrict__ idxl, const int* __restrict__ cnt,
    float* __restrict__ part) {
  int zid = blockIdx.z;
  int kexp = zid >> 2, s = zid & 3;
  int nk = cnt[kexp];
  int rowbase = blockIdx.x * 64;
  if (rowbase >= nk) return;
  int h0 = blockIdx.y * 64;
  int tid = threadIdx.x;
  int lane = tid & 63, wv = tid >> 6;

  __shared__ __align__(16) u16 As[2][4096];
  __shared__ __align__(16) u16 Bs[2][4096];
  __shared__ int sidx[64];

  const int* idxk = idxl + kexp * NB;
  if (tid < 64) {
    int p = rowbase + tid;
    sidx[tid] = idxk[p < nk ? p : nk - 1];
  }

  // A staging: thread loads 2 rows x 8 k (f32), packs to bf16, swizzled ds_write
  int r0 = tid >> 3, r1 = r0 + 32, kg = tid & 7;
  int p0 = rowbase + r0; if (p0 > nk - 1) p0 = nk - 1;
  int p1 = rowbase + r1; if (p1 > nk - 1) p1 = nk - 1;
  size_t kbase = (size_t)s * KSLICE;
  const float* zr0 = z + (size_t)idxk[p0] * LDIM + kbase + kg * 8;
  const float* zr1 = z + (size_t)idxk[p1] * LDIM + kbase + kg * 8;
  int swA0 = r0 * 64 + ((kg * 8) ^ ((r0 & 7) * 8));
  int swA1 = r1 * 64 + ((kg * 8) ^ ((r1 & 7) * 8));

  // B staging via global_load_lds: linear LDS dest, inverse-swizzled global source.
  // call c: linear byte = wv*2048 + c*1024 + lane*16 -> row r = wv*16+c*8+(lane>>3),
  // chunk_lin = lane&7, chunk_src = (lane&7)^(lane>>3)  (r&7 == lane>>3)
  const u16* bsrc0 = W1t + ((size_t)kexp * HDIM + h0 + wv * 16 + (lane >> 3)) * LDIM +
                     kbase + (size_t)(((lane & 7) ^ (lane >> 3)) * 8);
  const u16* bsrc1 = bsrc0 + 8 * LDIM;

  int fr = lane & 15, kgl = (lane >> 4) * 8;
  int wr = (wv >> 1) * 32, wc = (wv & 1) * 32;
  int ra0 = wr + fr, ra1 = ra0 + 16, ca0 = wc + fr, ca1 = ca0 + 16;
  int xA0 = (ra0 & 7) * 8, xA1 = (ra1 & 7) * 8, xB0 = (ca0 & 7) * 8, xB1 = (ca1 & 7) * 8;

  f32x4 acc[2][2] = {};
  float4 a0, a1, a2, a3;

  // prologue: stage tile 0 into buffer 0
  {
    char* lb = (char*)&Bs[0][0] + wv * 2048;
    gll16(bsrc0, lb);
    gll16(bsrc1, lb + 1024);
    a0 = *(const float4*)(zr0);
    a1 = *(const float4*)(zr0 + 4);
    a2 = *(const float4*)(zr1);
    a3 = *(const float4*)(zr1 + 4);
    uint4 pa0, pa1;
    pa0.x = pack2(a0.x, a0.y); pa0.y = pack2(a0.z, a0.w);
    pa0.z = pack2(a1.x, a1.y); pa0.w = pack2(a1.z, a1.w);
    pa1.x = pack2(a2.x, a2.y); pa1.y = pack2(a2.z, a2.w);
    pa1.z = pack2(a3.x, a3.y); pa1.w = pack2(a3.z, a3.w);
    *(uint4*)&As[0][swA0] = pa0;
    *(uint4*)&As[0][swA1] = pa1;
  }
  __syncthreads();

  int cur = 0;
  for (int t = 0; t < NT; ++t) {
    int nxt = cur ^ 1;
    bool pre = (t + 1 < NT);
    if (pre) {
      int off = (t + 1) * BK;
      char* lb = (char*)&Bs[nxt][0] + wv * 2048;
      gll16(bsrc0 + off, lb);
      gll16(bsrc1 + off, lb + 1024);
      a0 = *(const float4*)(zr0 + off);
      a1 = *(const float4*)(zr0 + off + 4);
      a2 = *(const float4*)(zr1 + off);
      a3 = *(const float4*)(zr1 + off + 4);
    }
    const u16* Ac = &As[cur][0];
    const u16* Bc = &Bs[cur][0];
#pragma unroll
    for (int ks = 0; ks < 2; ++ks) {
      int kk = ks * 32 + kgl;
      short8 af0 = *(const short8*)&Ac[ra0 * 64 + (kk ^ xA0)];
      short8 af1 = *(const short8*)&Ac[ra1 * 64 + (kk ^ xA1)];
      short8 bf0 = *(const short8*)&Bc[ca0 * 64 + (kk ^ xB0)];
      short8 bf1 = *(const short8*)&Bc[ca1 * 64 + (kk ^ xB1)];
      acc[0][0] = __builtin_amdgcn_mfma_f32_16x16x32_bf16(af0, bf0, acc[0][0], 0, 0, 0);
      acc[0][1] = __builtin_amdgcn_mfma_f32_16x16x32_bf16(af0, bf1, acc[0][1], 0, 0, 0);
      acc[1][0] = __builtin_amdgcn_mfma_f32_16x16x32_bf16(af1, bf0, acc[1][0], 0, 0, 0);
      acc[1][1] = __builtin_amdgcn_mfma_f32_16x16x32_bf16(af1, bf1, acc[1][1], 0, 0, 0);
    }
    if (pre) {
      uint4 pa0, pa1;
      pa0.x = pack2(a0.x, a0.y); pa0.y = pack2(a0.z, a0.w);
      pa0.z = pack2(a1.x, a1.y); pa0.w = pack2(a1.z, a1.w);
      pa1.x = pack2(a2.x, a2.y); pa1.y = pack2(a2.z, a2.w);
      pa1.z = pack2(a3.x, a3.y); pa1.w = pack2(a3.z, a3.w);
      *(uint4*)&As[nxt][swA0] = pa0;
      *(uint4*)&As[nxt][swA1] = pa1;
    }
    __syncthreads();
    cur = nxt;
  }

  // store raw partial tile to part[s][b][h]
  float* pdst = part + (size_t)s * NB * HDIM;
#pragma unroll
  for (int rb = 0; rb < 2; ++rb)
#pragma unroll
    for (int cb = 0; cb < 2; ++cb)
#pragma unroll
      for (int i = 0; i < 4; ++i) {
        int row = wr + rb * 16 + (lane >> 4) * 4 + i;
        int col = wc + cb * 16 + fr;
        if (rowbase + row < nk)
          pdst[(size_t)sidx[row] * HDIM + h0 + col] = acc[rb][cb][i];
      }
}

// ---------------- Kernel 5b: epilogue — sum partials, gelu, dot(v) -> logits ----------------
__global__ void ep_kernel(const float* __restrict__ part, const float* __restrict__ b1,
                          const float* __restrict__ v, const int* __restrict__ group,
                          float* __restrict__ logits) {
  int b = blockIdx.x;
  int t = threadIdx.x;
  int g = group[b];
  size_t o = (size_t)b * HDIM + t;
  const size_t SS = (size_t)NB * HDIM;
  float x = part[o] + part[o + SS] + part[o + 2 * SS] + part[o + 3 * SS] + b1[g * HDIM + t];
  float ge = 0.5f * x * (1.0f + erff(x * 0.70710678118654752f));
  float y = ge * v[g * HDIM + t];
#pragma unroll
  for (int off = 32; off; off >>= 1) y += __shfl_down(y, off);
  __shared__ float red[4];
  int lane = t & 63, wv = t >> 6;
  if (lane == 0) red[wv] = y;
  __syncthreads();
  if (t == 0) logits[b] = red[0] + red[1] + red[2] + red[3];
}

// ---------------- Kernel 6: per-channel softmax * q ----------------
__global__ void softmax_kernel(const float* __restrict__ logits, const float* __restrict__ cbias,
                               const int* __restrict__ group, const float* __restrict__ q,
                               const int* __restrict__ ch, float* __restrict__ out) {
  int c = blockIdx.x;
  int tid = threadIdx.x;
  __shared__ float red[256];
  float m = -3.4e38f;
  for (int i = tid; i < NB; i += 256)
    if (ch[i] == c) {
      float x = logits[i] + cbias[group[i]];
      m = fmaxf(m, x);
    }
  red[tid] = m;
  __syncthreads();
  for (int s = 128; s > 0; s >>= 1) {
    if (tid < s) red[tid] = fmaxf(red[tid], red[tid + s]);
    __syncthreads();
  }
  m = red[0];
  __syncthreads();
  float sum = 0.f;
  for (int i = tid; i < NB; i += 256)
    if (ch[i] == c) sum += expf(logits[i] + cbias[group[i]] - m);
  red[tid] = sum;
  __syncthreads();
  for (int s = 128; s > 0; s >>= 1) {
    if (tid < s) red[tid] += red[tid + s];
    __syncthreads();
  }
  float S = red[0];
  for (int i = tid; i < NB; i += 256)
    if (ch[i] == c) out[i] = q[i] * expf(logits[i] + cbias[group[i]] - m) / S;
}

extern "C" void kernel_launch(void* const* d_in, const int* in_sizes, int n_in,
                              void* d_out, int out_size, void* d_ws, size_t ws_size,
                              hipStream_t stream) {
  const float* z  = (const float*)d_in[0];
  const float* q  = (const float*)d_in[1];
  const int*   ch = (const int*)d_in[2];
  const float* W1 = (const float*)d_in[3];
  const float* b1 = (const float*)d_in[4];
  const float* W2 = (const float*)d_in[5];
  const float* b2 = (const float*)d_in[6];
  const float* Wh = (const float*)d_in[7];
  const float* bh = (const float*)d_in[8];
  float* out = (float*)d_out;

  float* wsf    = (float*)d_ws;
  float* logits = wsf;                     // 4096 f32
  int*   cnt    = (int*)(wsf + 4096);      // 4 int
  float* uq_th  = wsf + 4100;              // 8
  float* lq_th  = wsf + 4108;              // 8
  float* cbias  = wsf + 4116;              // 4
  float* v      = wsf + 4120;              // 768
  int*   group  = (int*)(wsf + 4888);      // 4096 int
  int*   idxl   = (int*)(wsf + 8984);      // 3*4096 int
  u16*   W1t    = (u16*)(wsf + 21272);     // 3*256*8192 bf16 (byte off 85088, 16B aligned)
  float* part   = wsf + 3167000;           // 4*4096*256 f32 (16.8 MB)

  hipMemsetAsync((char*)d_ws + 4096 * 4, 0, 16, stream);  // zero cnt
  hipLaunchKernelGGL(thresh_kernel, dim3(NCH), dim3(256), 0, stream, q, ch, uq_th, lq_th);
  hipLaunchKernelGGL(group_kernel, dim3(16), dim3(256), 0, stream, q, ch, uq_th, lq_th, group, cnt, idxl);
  hipLaunchKernelGGL(v_kernel, dim3(192), dim3(256), 0, stream, W2, Wh, v);
  hipLaunchKernelGGL(cbias_kernel, dim3(1), dim3(192), 0, stream, b2, Wh, bh, cbias);
  hipLaunchKernelGGL(transpose_kernel, dim3(128, 4, 3), dim3(256), 0, stream, W1, W1t);
  hipLaunchKernelGGL(gemm_kernel, dim3(64, 4, NEXP * KSPLIT), dim3(256), 0, stream,
                     z, W1t, idxl, cnt, part);
  hipLaunchKernelGGL(ep_kernel, dim3(NB), dim3(256), 0, stream, part, b1, v, group, logits);
  hipLaunchKernelGGL(softmax_kernel, dim3(NCH), dim3(256), 0, stream, logits, cbias, group, q, ch, out);
}